// Round 3
// baseline (1618.899 us; speedup 1.0000x reference)
//
#include <hip/hip_runtime.h>
#include <hip/hip_bf16.h>

// ---------- bf16 helpers (bit-level, fp32 internal math) ----------
static __device__ __forceinline__ float bf2f(unsigned short h) {
    unsigned int u = ((unsigned int)h) << 16;
    float f;
    __builtin_memcpy(&f, &u, 4);
    return f;
}
static __device__ __forceinline__ unsigned short f2bf(float f) {
    unsigned int u;
    __builtin_memcpy(&u, &f, 4);
    u = (u + 0x7FFFu + ((u >> 16) & 1u)) >> 16;   // RNE
    return (unsigned short)u;
}

// fp32 param block layout (offsets in floats)
#define P_NAM 0
#define P_W1 640
#define P_B1 33408
#define P_W2 33440
#define P_B2 66208
#define P_W3 66272
#define P_B3 131808
#define P_K1W 131872
#define P_K1B 148256
#define P_K2W 148512
#define P_K2B 181280
#define P_K3W 181408
#define P_K3B 214176
#define P_Q1W 214432
#define P_Q1B 230816
#define P_Q2W 231072
#define P_Q2B 263840
#define P_Q3W 263968
#define P_Q3B 268064
#define P_AW 268096
#define P_AB 276288
#define P_TOTAL 276544

// ============================================================
// K0: dtype detect. flag=1 if inputs are fp32, 0 if bf16.
// ============================================================
__global__ void k_detect(const unsigned short* __restrict__ x, int* __restrict__ flag) {
    const int lane = threadIdx.x;           // 0..63
    const unsigned short h = x[2 * lane];
    const int e = (h >> 7) & 0xFF;
    const int ok = (e >= 110 && e <= 140) ? 1 : 0;
    unsigned long long m = __ballot(ok);
    if (lane == 0) *flag = (__popcll(m) >= 48) ? 0 : 1;
}

// ============================================================
// K0b: convert all 21 param tensors into canonical fp32 block
// ============================================================
struct ParamDesc {
    const void* src[21];
    int len[21];
    int dst[21];
};

__global__ __launch_bounds__(256) void k_convert(ParamDesc pd, const int* __restrict__ flag,
                                                 float* __restrict__ out) {
    int idx = blockIdx.x * 256 + threadIdx.x;
    const int isf = *flag;
    for (int t = 0; t < 21; ++t) {
        const int l = pd.len[t];
        if (idx < l) {
            float v = isf ? ((const float*)pd.src[t])[idx]
                          : bf2f(((const unsigned short*)pd.src[t])[idx]);
            out[pd.dst[t] + idx] = v;
            return;
        }
        idx -= l;
    }
}

// ============================================================
// K1: grid_sample -> neigh (bf16), layout [n=b*5+l][c][256][128]
// ============================================================
__global__ __launch_bounds__(128) void k_gridsample(
    const void* __restrict__ xv,
    const float* __restrict__ P,
    const int* __restrict__ flag,
    unsigned short* __restrict__ neigh)
{
    const int n = blockIdx.x;        // 0..19
    const int h = blockIdx.y;        // 0..255
    const int w = threadIdx.x;       // 0..127
    const int b = n / 5, l = n - b * 5;
    const float* th = P + P_NAM + (b * 25 + l) * 6;   // nam[b][0][l]
    const float t00 = th[0], t01 = th[1], t02 = th[2];
    const float t10 = th[3], t11 = th[4], t12 = th[5];

    const float gxn = ((float)w + 0.5f) * (2.0f / 128.0f) - 1.0f;
    const float gyn = ((float)h + 0.5f) * (2.0f / 256.0f) - 1.0f;
    const float gx = t00 * gxn + t01 * gyn + t02;
    const float gy = t10 * gxn + t11 * gyn + t12;
    const float xs = ((gx + 1.0f) * 128.0f - 1.0f) * 0.5f;
    const float ys = ((gy + 1.0f) * 256.0f - 1.0f) * 0.5f;
    const float x0f = floorf(xs), y0f = floorf(ys);
    const int ix0 = (int)x0f, iy0 = (int)y0f;
    const int ix1 = ix0 + 1, iy1 = iy0 + 1;
    const float wx1 = xs - x0f, wx0 = 1.0f - wx1;
    const float wy1 = ys - y0f, wy0 = 1.0f - wy1;

    const float mx0 = (ix0 >= 0 && ix0 < 128) ? 1.0f : 0.0f;
    const float mx1 = (ix1 >= 0 && ix1 < 128) ? 1.0f : 0.0f;
    const float my0 = (iy0 >= 0 && iy0 < 256) ? 1.0f : 0.0f;
    const float my1 = (iy1 >= 0 && iy1 < 256) ? 1.0f : 0.0f;
    const int cx0 = min(max(ix0, 0), 127), cx1 = min(max(ix1, 0), 127);
    const int cy0 = min(max(iy0, 0), 255), cy1 = min(max(iy1, 0), 255);

    const float m00 = mx0 * my0, m10 = mx1 * my0, m01 = mx0 * my1, m11 = mx1 * my1;
    const int o00 = cy0 * 128 + cx0, o10 = cy0 * 128 + cx1;
    const int o01 = cy1 * 128 + cx0, o11 = cy1 * 128 + cx1;

    unsigned short* outp = neigh + n * 64 * 32768 + h * 128 + w;
    if (*flag) {
        const float* img = ((const float*)xv) + (size_t)n * 64 * 32768;
        for (int c = 0; c < 64; ++c) {
            const float* ic = img + c * 32768;
            const float r = (ic[o00] * m00 * wx0 + ic[o10] * m10 * wx1) * wy0 +
                            (ic[o01] * m01 * wx0 + ic[o11] * m11 * wx1) * wy1;
            outp[c * 32768] = f2bf(r);
        }
    } else {
        const unsigned short* img = ((const unsigned short*)xv) + (size_t)n * 64 * 32768;
        for (int c = 0; c < 64; ++c) {
            const unsigned short* ic = img + c * 32768;
            const float r = (bf2f(ic[o00]) * m00 * wx0 + bf2f(ic[o10]) * m10 * wx1) * wy0 +
                            (bf2f(ic[o01]) * m01 * wx0 + bf2f(ic[o11]) * m11 * wx1) * wy1;
            outp[c * 32768] = f2bf(r);
        }
    }
}

// ============================================================
// K2: conv1 64->32ch, 4x4 s2 p1, in 256x128 -> out 128x64, ReLU
// ============================================================
__global__ __launch_bounds__(128) void k_conv1(
    const unsigned short* __restrict__ in,   // neigh (bf16)
    const float* __restrict__ P,
    unsigned short* __restrict__ out)        // (20,32,128,64)
{
    __shared__ unsigned short s_in[8 * 18 * 66];
    __shared__ float s_w[128 * 32];
    const float* pw = P + P_W1;
    const float* pb = P + P_B1;
    const int n = blockIdx.x;
    const int oy0 = blockIdx.y * 8;
    const int ox0 = blockIdx.z * 32;
    const int tid = threadIdx.x;
    const int ty = tid >> 4;
    const int tx = tid & 15;

    float accA[32], accB[32];
#pragma unroll
    for (int i = 0; i < 32; ++i) { accA[i] = 0.0f; accB[i] = 0.0f; }

    for (int ic0 = 0; ic0 < 64; ic0 += 8) {
        __syncthreads();
        for (int e = tid; e < 9504; e += 128) {
            int icl = e / 1188; int rem = e - icl * 1188;
            int r = rem / 66;    int col = rem - r * 66;
            int gy = 2 * oy0 - 1 + r;
            int gx = 2 * ox0 - 1 + col;
            unsigned short v = 0;
            if (gy >= 0 && gy < 256 && gx >= 0 && gx < 128)
                v = in[(n * 64 + ic0 + icl) * 32768 + gy * 128 + gx];
            s_in[e] = v;
        }
        for (int e = tid; e < 4096; e += 128) {
            int t = e >> 5; int oc = e & 31;
            int icl = t >> 4; int tap = t & 15;
            s_w[e] = pw[oc * 1024 + (ic0 + icl) * 16 + tap];
        }
        __syncthreads();
        for (int icl = 0; icl < 8; ++icl) {
            const int ib = (icl * 18 + 2 * ty) * 66 + 2 * tx;
#pragma unroll
            for (int ky = 0; ky < 4; ++ky) {
#pragma unroll
                for (int kx = 0; kx < 4; ++kx) {
                    const float va = bf2f(s_in[ib + ky * 66 + kx]);
                    const float vb = bf2f(s_in[ib + ky * 66 + kx + 32]);
                    const float4* wp = (const float4*)&s_w[(icl * 16 + ky * 4 + kx) * 32];
#pragma unroll
                    for (int o = 0; o < 8; ++o) {
                        const float4 w4 = wp[o];
                        accA[4 * o + 0] += w4.x * va;  accB[4 * o + 0] += w4.x * vb;
                        accA[4 * o + 1] += w4.y * va;  accB[4 * o + 1] += w4.y * vb;
                        accA[4 * o + 2] += w4.z * va;  accB[4 * o + 2] += w4.z * vb;
                        accA[4 * o + 3] += w4.w * va;  accB[4 * o + 3] += w4.w * vb;
                    }
                }
            }
        }
    }
    const int oy = oy0 + ty;
#pragma unroll
    for (int oc = 0; oc < 32; ++oc) {
        const float bb = pb[oc];
        float a = accA[oc] + bb; a = a > 0.0f ? a : 0.0f;
        float b2 = accB[oc] + bb; b2 = b2 > 0.0f ? b2 : 0.0f;
        unsigned short* op = out + (n * 32 + oc) * 8192 + oy * 64 + ox0 + tx;
        op[0]  = f2bf(a);
        op[16] = f2bf(b2);
    }
}

// ============================================================
// K3: conv2 32->64ch, in 128x64 -> out 64x32, ReLU
// ============================================================
__global__ __launch_bounds__(128) void k_conv2(
    const unsigned short* __restrict__ in,   // (20,32,128,64)
    const float* __restrict__ P,
    unsigned short* __restrict__ out)        // (20,64,64,32)
{
    __shared__ unsigned short s_in[8 * 18 * 66];
    __shared__ float s_w[128 * 32];
    const float* pw = P + P_W2;
    const float* pb = P + P_B2;
    const int n = blockIdx.x;
    const int oy0 = blockIdx.y * 8;
    const int ocb = blockIdx.z * 32;
    const int tid = threadIdx.x;
    const int ty = tid >> 4;
    const int tx = tid & 15;

    float accA[32], accB[32];
#pragma unroll
    for (int i = 0; i < 32; ++i) { accA[i] = 0.0f; accB[i] = 0.0f; }

    for (int ic0 = 0; ic0 < 32; ic0 += 8) {
        __syncthreads();
        for (int e = tid; e < 9504; e += 128) {
            int icl = e / 1188; int rem = e - icl * 1188;
            int r = rem / 66;    int col = rem - r * 66;
            int gy = 2 * oy0 - 1 + r;
            int gx = -1 + col;
            unsigned short v = 0;
            if (gy >= 0 && gy < 128 && gx >= 0 && gx < 64)
                v = in[(n * 32 + ic0 + icl) * 8192 + gy * 64 + gx];
            s_in[e] = v;
        }
        for (int e = tid; e < 4096; e += 128) {
            int t = e >> 5; int oc = e & 31;
            int icl = t >> 4; int tap = t & 15;
            s_w[e] = pw[(ocb + oc) * 512 + (ic0 + icl) * 16 + tap];
        }
        __syncthreads();
        for (int icl = 0; icl < 8; ++icl) {
            const int ib = (icl * 18 + 2 * ty) * 66 + 2 * tx;
#pragma unroll
            for (int ky = 0; ky < 4; ++ky) {
#pragma unroll
                for (int kx = 0; kx < 4; ++kx) {
                    const float va = bf2f(s_in[ib + ky * 66 + kx]);
                    const float vb = bf2f(s_in[ib + ky * 66 + kx + 32]);
                    const float4* wp = (const float4*)&s_w[(icl * 16 + ky * 4 + kx) * 32];
#pragma unroll
                    for (int o = 0; o < 8; ++o) {
                        const float4 w4 = wp[o];
                        accA[4 * o + 0] += w4.x * va;  accB[4 * o + 0] += w4.x * vb;
                        accA[4 * o + 1] += w4.y * va;  accB[4 * o + 1] += w4.y * vb;
                        accA[4 * o + 2] += w4.z * va;  accB[4 * o + 2] += w4.z * vb;
                        accA[4 * o + 3] += w4.w * va;  accB[4 * o + 3] += w4.w * vb;
                    }
                }
            }
        }
    }
    const int oy = oy0 + ty;
#pragma unroll
    for (int oc = 0; oc < 32; ++oc) {
        const float bb = pb[ocb + oc];
        float a = accA[oc] + bb; a = a > 0.0f ? a : 0.0f;
        float b2 = accB[oc] + bb; b2 = b2 > 0.0f ? b2 : 0.0f;
        unsigned short* op = out + (n * 64 + ocb + oc) * 2048 + oy * 32 + tx;
        op[0]  = f2bf(a);
        op[16] = f2bf(b2);
    }
}

// ============================================================
// K4: conv3 64->64ch, in 64x32 -> out 32x16, ReLU, fused avg-pool sum
// ============================================================
__global__ __launch_bounds__(128) void k_conv3pool(
    const unsigned short* __restrict__ in,   // (20,64,64,32)
    const float* __restrict__ P,
    float* __restrict__ pooled)              // (20,64) sums
{
    __shared__ unsigned short s_in[8 * 34 * 34];
    __shared__ float s_w[128 * 32];
    const float* pw = P + P_W3;
    const float* pb = P + P_B3;
    const int n = blockIdx.x;
    const int oy0 = blockIdx.y * 16;
    const int ocb = blockIdx.z * 32;
    const int tid = threadIdx.x;
    const int ty = tid >> 4;
    const int tx = tid & 15;

    float accA[32], accB[32];
#pragma unroll
    for (int i = 0; i < 32; ++i) { accA[i] = 0.0f; accB[i] = 0.0f; }

    for (int ic0 = 0; ic0 < 64; ic0 += 8) {
        __syncthreads();
        for (int e = tid; e < 9248; e += 128) {
            int icl = e / 1156; int rem = e - icl * 1156;
            int r = rem / 34;    int col = rem - r * 34;
            int gy = 2 * oy0 - 1 + r;
            int gx = -1 + col;
            unsigned short v = 0;
            if (gy >= 0 && gy < 64 && gx >= 0 && gx < 32)
                v = in[(n * 64 + ic0 + icl) * 2048 + gy * 32 + gx];
            s_in[e] = v;
        }
        for (int e = tid; e < 4096; e += 128) {
            int t = e >> 5; int oc = e & 31;
            int icl = t >> 4; int tap = t & 15;
            s_w[e] = pw[(ocb + oc) * 1024 + (ic0 + icl) * 16 + tap];
        }
        __syncthreads();
        for (int icl = 0; icl < 8; ++icl) {
            const int ibA = (icl * 34 + 2 * ty) * 34 + 2 * tx;
#pragma unroll
            for (int ky = 0; ky < 4; ++ky) {
#pragma unroll
                for (int kx = 0; kx < 4; ++kx) {
                    const float va = bf2f(s_in[ibA + ky * 34 + kx]);
                    const float vb = bf2f(s_in[ibA + ky * 34 + kx + 16 * 34]);
                    const float4* wp = (const float4*)&s_w[(icl * 16 + ky * 4 + kx) * 32];
#pragma unroll
                    for (int o = 0; o < 8; ++o) {
                        const float4 w4 = wp[o];
                        accA[4 * o + 0] += w4.x * va;  accB[4 * o + 0] += w4.x * vb;
                        accA[4 * o + 1] += w4.y * va;  accB[4 * o + 1] += w4.y * vb;
                        accA[4 * o + 2] += w4.z * va;  accB[4 * o + 2] += w4.z * vb;
                        accA[4 * o + 3] += w4.w * va;  accB[4 * o + 3] += w4.w * vb;
                    }
                }
            }
        }
    }
    const int lane = tid & 63;
#pragma unroll
    for (int oc = 0; oc < 32; ++oc) {
        const float bb = pb[ocb + oc];
        float a = accA[oc] + bb; a = a > 0.0f ? a : 0.0f;
        float b2 = accB[oc] + bb; b2 = b2 > 0.0f ? b2 : 0.0f;
        float v = a + b2;
        for (int off = 32; off > 0; off >>= 1) v += __shfl_down(v, off, 64);
        if (lane == 0) atomicAdd(&pooled[n * 64 + ocb + oc], v);
    }
}

// ============================================================
// K5: attention — MLPs + softmax. 4 blocks (per batch), 256 thr
// ============================================================
__global__ __launch_bounds__(256) void k_attn(
    const float* __restrict__ P,
    const float* __restrict__ pooled,       // (20,64) sums
    float* __restrict__ attn)               // (4,5)
{
    __shared__ float sfeat[320], sh1[1280], sh2[640], skeys[1280];
    __shared__ float sq1[256], sq2[128], sq3[32], sqv[256], sred[4], slog[5];
    const int b = blockIdx.x, t = threadIdx.x;

    for (int i = t; i < 320; i += 256) sfeat[i] = pooled[b * 320 + i] * (1.0f / 512.0f);
    __syncthreads();

    {
        const float* w = P + P_K1W; const float* bb = P + P_K1B;
        for (int l = 0; l < 5; ++l) {
            float s = bb[t];
            for (int c = 0; c < 64; ++c) s += w[t * 64 + c] * sfeat[l * 64 + c];
            sh1[l * 256 + t] = fmaxf(s, 0.0f);
        }
        const float* wq = P + P_Q1W; const float* bq = P + P_Q1B;
        float s = bq[t];
        for (int c = 0; c < 64; ++c) s += wq[t * 64 + c] * sfeat[c];
        sq1[t] = fmaxf(s, 0.0f);
    }
    __syncthreads();
    if (t < 128) {
        const float* w = P + P_K2W; const float* bb = P + P_K2B;
        for (int l = 0; l < 5; ++l) {
            float s = bb[t];
            for (int k = 0; k < 256; ++k) s += w[t * 256 + k] * sh1[l * 256 + k];
            sh2[l * 128 + t] = fmaxf(s, 0.0f);
        }
        const float* wq = P + P_Q2W; const float* bq = P + P_Q2B;
        float s = bq[t];
        for (int k = 0; k < 256; ++k) s += wq[t * 256 + k] * sq1[k];
        sq2[t] = fmaxf(s, 0.0f);
    }
    __syncthreads();
    {
        const float* w = P + P_K3W; const float* bb = P + P_K3B;
        for (int l = 0; l < 5; ++l) {
            float s = bb[t];
            for (int k = 0; k < 128; ++k) s += w[t * 128 + k] * sh2[l * 128 + k];
            skeys[l * 256 + t] = s;   // no relu on layer 3
        }
    }
    if (t < 32) {
        const float* wq = P + P_Q3W; const float* bq = P + P_Q3B;
        float s = bq[t];
        for (int k = 0; k < 128; ++k) s += wq[t * 128 + k] * sq2[k];
        sq3[t] = s;
    }
    __syncthreads();
    {
        const float* w = P + P_AW; const float* bb = P + P_AB;
        float s = bb[t];
        for (int k = 0; k < 32; ++k) s += w[t * 32 + k] * sq3[k];
        sqv[t] = s;
    }
    __syncthreads();
    for (int l = 0; l < 5; ++l) {
        float v = skeys[l * 256 + t] * sqv[t];
        for (int off = 32; off > 0; off >>= 1) v += __shfl_down(v, off, 64);
        if ((t & 63) == 0) sred[t >> 6] = v;
        __syncthreads();
        if (t == 0) slog[l] = sred[0] + sred[1] + sred[2] + sred[3];
        __syncthreads();
    }
    if (t == 0) {
        float m = slog[0];
        for (int l = 1; l < 5; ++l) m = fmaxf(m, slog[l]);
        float e[5], s = 0.0f;
        for (int l = 0; l < 5; ++l) { e[l] = expf(slog[l] - m); s += e[l]; }
        const float inv = 1.0f / s;
        for (int l = 0; l < 5; ++l) attn[b * 5 + l] = e[l] * inv;
    }
}

// ============================================================
// K6: out[b,c,h,w] = sum_l attn[b,l] * neigh[b,l,c,h,w]  (fp32 out)
// ============================================================
__global__ __launch_bounds__(256) void k_final(
    const unsigned short* __restrict__ neigh,
    const float* __restrict__ attn,
    float* __restrict__ out)
{
    const int idx = blockIdx.x * 256 + threadIdx.x;
    const int b = idx >> 21;
    const int chw = idx & 2097151;
    const unsigned short* p = neigh + b * 5 * 2097152 + chw;
    const float* a = attn + b * 5;
    float s = a[0] * bf2f(p[0]);
    s += a[1] * bf2f(p[1 * 2097152]);
    s += a[2] * bf2f(p[2 * 2097152]);
    s += a[3] * bf2f(p[3 * 2097152]);
    s += a[4] * bf2f(p[4 * 2097152]);
    out[idx] = s;
}

// ============================================================
extern "C" void kernel_launch(void* const* d_in, const int* in_sizes, int n_in,
                              void* d_out, int out_size, void* d_ws, size_t ws_size,
                              hipStream_t stream) {
    // workspace layout (bytes)
    const size_t OFF_FLAG  = 0;                       // int
    const size_t OFF_PARAM = 256;                     // P_TOTAL f32 = 1,106,176 B
    const size_t OFF_NEIGH = 1106432;                 // 20*64*256*128 bf16 = 83,886,080
    const size_t OFF_C1    = OFF_NEIGH + 83886080;    // 20*32*128*64 bf16 = 10,485,760
    const size_t OFF_C2    = OFF_C1 + 10485760;       // 20*64*64*32 bf16  =  5,242,880
    const size_t OFF_POOL  = OFF_C2 + 5242880;        // 20*64 f32 = 5,120
    const size_t OFF_ATTN  = OFF_POOL + 5120;         // 4*5 f32 = 80
    const size_t NEED      = OFF_ATTN + 80;
    if (ws_size < NEED) return;  // clean fail signal (absmax == max|ref|)

    char* ws = (char*)d_ws;
    int*   flag   = (int*)(ws + OFF_FLAG);
    float* params = (float*)(ws + OFF_PARAM);
    unsigned short* neigh = (unsigned short*)(ws + OFF_NEIGH);
    unsigned short* c1    = (unsigned short*)(ws + OFF_C1);
    unsigned short* c2    = (unsigned short*)(ws + OFF_C2);
    float* pooled         = (float*)(ws + OFF_POOL);
    float* attn           = (float*)(ws + OFF_ATTN);

    ParamDesc pd;
    const int srcIdx[21] = {2,3,4,5,6,7,8,9,10,11,12,13,14,15,16,17,18,19,20,21,22};
    const int lens[21]   = {600,32768,32,32768,64,65536,64,16384,256,32768,128,
                            32768,256,16384,256,32768,128,4096,32,8192,256};
    const int dsts[21]   = {P_NAM,P_W1,P_B1,P_W2,P_B2,P_W3,P_B3,P_K1W,P_K1B,P_K2W,P_K2B,
                            P_K3W,P_K3B,P_Q1W,P_Q1B,P_Q2W,P_Q2B,P_Q3W,P_Q3B,P_AW,P_AB};
    for (int t = 0; t < 21; ++t) {
        pd.src[t] = d_in[srcIdx[t]];
        pd.len[t] = lens[t];
        pd.dst[t] = dsts[t];
    }

    hipMemsetAsync(pooled, 0, 5120, stream);

    k_detect<<<1, 64, 0, stream>>>((const unsigned short*)d_in[0], flag);
    k_convert<<<1081, 256, 0, stream>>>(pd, flag, params);
    k_gridsample<<<dim3(20, 256, 1), 128, 0, stream>>>(d_in[0], params, flag, neigh);
    k_conv1<<<dim3(20, 16, 2), 128, 0, stream>>>(neigh, params, c1);
    k_conv2<<<dim3(20, 8, 2), 128, 0, stream>>>(c1, params, c2);
    k_conv3pool<<<dim3(20, 2, 2), 128, 0, stream>>>(c2, params, pooled);
    k_attn<<<4, 256, 0, stream>>>(params, pooled, attn);
    k_final<<<32768, 256, 0, stream>>>(neigh, attn, (float*)d_out);
}

// Round 4
// 521.088 us; speedup vs baseline: 3.1068x; 3.1068x over previous
//
#include <hip/hip_runtime.h>
#include <hip/hip_bf16.h>

typedef __attribute__((ext_vector_type(8))) short short8;
typedef __attribute__((ext_vector_type(8))) unsigned short ushort8;
typedef __attribute__((ext_vector_type(4))) float floatx4;

// ---------- bf16 helpers (bit-level, fp32 internal math) ----------
static __device__ __forceinline__ float bf2f(unsigned short h) {
    unsigned int u = ((unsigned int)h) << 16;
    float f;
    __builtin_memcpy(&f, &u, 4);
    return f;
}
static __device__ __forceinline__ unsigned short f2bf(float f) {
    unsigned int u;
    __builtin_memcpy(&u, &f, 4);
    u = (u + 0x7FFFu + ((u >> 16) & 1u)) >> 16;   // RNE
    return (unsigned short)u;
}

// fp32 param block layout (offsets in floats) — biases + attn MLPs + nam only
#define P_NAM 0
#define P_B1 600
#define P_B2 632
#define P_B3 696
#define P_K1W 760
#define P_K1B 17144
#define P_K2W 17400
#define P_K2B 50168
#define P_K3W 50296
#define P_K3B 83064
#define P_Q1W 83320
#define P_Q1B 99704
#define P_Q2W 99960
#define P_Q2B 132728
#define P_Q3W 132856
#define P_Q3B 136952
#define P_AW 136984
#define P_AB 145176
#define P_TOTAL 145432

// ============================================================
// K0: dtype detect. flag=1 if inputs are fp32, 0 if bf16.
// ============================================================
__global__ void k_detect(const unsigned short* __restrict__ x, int* __restrict__ flag) {
    const int lane = threadIdx.x;
    const unsigned short h = x[2 * lane];
    const int e = (h >> 7) & 0xFF;
    const int ok = (e >= 110 && e <= 140) ? 1 : 0;
    unsigned long long m = __ballot(ok);
    if (lane == 0) *flag = (__popcll(m) >= 48) ? 0 : 1;
}

// ============================================================
// K0b: convert 18 small param tensors into canonical fp32 block
// ============================================================
struct ParamDesc {
    const void* src[18];
    int len[18];
    int dst[18];
};

__global__ __launch_bounds__(256) void k_convert(ParamDesc pd, const int* __restrict__ flag,
                                                 float* __restrict__ out) {
    int idx = blockIdx.x * 256 + threadIdx.x;
    const int isf = *flag;
    for (int t = 0; t < 18; ++t) {
        const int l = pd.len[t];
        if (idx < l) {
            float v = isf ? ((const float*)pd.src[t])[idx]
                          : bf2f(((const unsigned short*)pd.src[t])[idx]);
            out[pd.dst[t] + idx] = v;
            return;
        }
        idx -= l;
    }
}

// ============================================================
// K0c: pack conv weights into MFMA B-fragment blobs (bf16)
// blob1: [ky2b][c1b][s2b][t1b][lane6b][j3b]  (conv1: 32oc,64ic)
// blob2: [ky2b][s2b][t2b][lane6b][j3b]       (conv2: 64oc,32ic)
// blob3: [ky2b][c1b][s2b][t2b][lane6b][j3b]  (conv3: 64oc,64ic)
// ============================================================
__global__ __launch_bounds__(256) void k_pack(
    const void* __restrict__ w1, const void* __restrict__ w2, const void* __restrict__ w3,
    const int* __restrict__ flag, short* __restrict__ blobs)
{
    const int idx = blockIdx.x * 256 + threadIdx.x;
    const int isf = *flag;
    if (idx < 32768) {
        int j = idx & 7, lane = (idx >> 3) & 63, t = (idx >> 9) & 1,
            s = (idx >> 10) & 3, c = (idx >> 12) & 1, ky = (idx >> 13) & 3;
        int kp = s * 32 + (lane >> 4) * 8 + j;
        int kx = kp >> 5, ic = c * 32 + (kp & 31), oc = t * 16 + (lane & 15);
        int si = oc * 1024 + ic * 16 + ky * 4 + kx;
        float v = isf ? ((const float*)w1)[si] : bf2f(((const unsigned short*)w1)[si]);
        blobs[idx] = (short)f2bf(v);
    } else if (idx < 65536) {
        int i2 = idx - 32768;
        int j = i2 & 7, lane = (i2 >> 3) & 63, t = (i2 >> 9) & 3,
            s = (i2 >> 11) & 3, ky = (i2 >> 13) & 3;
        int kp = s * 32 + (lane >> 4) * 8 + j;
        int kx = kp >> 5, ic = kp & 31, oc = t * 16 + (lane & 15);
        int si = oc * 512 + ic * 16 + ky * 4 + kx;
        float v = isf ? ((const float*)w2)[si] : bf2f(((const unsigned short*)w2)[si]);
        blobs[idx] = (short)f2bf(v);
    } else if (idx < 131072) {
        int i3 = idx - 65536;
        int j = i3 & 7, lane = (i3 >> 3) & 63, t = (i3 >> 9) & 3,
            s = (i3 >> 11) & 3, c = (i3 >> 13) & 1, ky = (i3 >> 14) & 3;
        int kp = s * 32 + (lane >> 4) * 8 + j;
        int kx = kp >> 5, ic = c * 32 + (kp & 31), oc = t * 16 + (lane & 15);
        int si = oc * 1024 + ic * 16 + ky * 4 + kx;
        float v = isf ? ((const float*)w3)[si] : bf2f(((const unsigned short*)w3)[si]);
        blobs[idx] = (short)f2bf(v);
    }
}

// ============================================================
// K1: grid_sample -> neighCL (bf16) channel-LAST [n][h 256][w 128][c 64]
// ============================================================
__global__ __launch_bounds__(128) void k_gridsample(
    const void* __restrict__ xv,
    const float* __restrict__ P,
    const int* __restrict__ flag,
    unsigned short* __restrict__ neighCL)
{
    __shared__ unsigned int s_t32[128 * 33];   // 128 px * 66 u16 (pad 2)
    unsigned short* s_t = (unsigned short*)s_t32;
    const int n = blockIdx.x;        // 0..19
    const int h = blockIdx.y;        // 0..255
    const int w = threadIdx.x;       // 0..127
    const int b = n / 5, l = n - b * 5;
    const float* th = P + P_NAM + (b * 25 + l) * 6;
    const float t00 = th[0], t01 = th[1], t02 = th[2];
    const float t10 = th[3], t11 = th[4], t12 = th[5];

    const float gxn = ((float)w + 0.5f) * (2.0f / 128.0f) - 1.0f;
    const float gyn = ((float)h + 0.5f) * (2.0f / 256.0f) - 1.0f;
    const float gx = t00 * gxn + t01 * gyn + t02;
    const float gy = t10 * gxn + t11 * gyn + t12;
    const float xs = ((gx + 1.0f) * 128.0f - 1.0f) * 0.5f;
    const float ys = ((gy + 1.0f) * 256.0f - 1.0f) * 0.5f;
    const float x0f = floorf(xs), y0f = floorf(ys);
    const int ix0 = (int)x0f, iy0 = (int)y0f;
    const int ix1 = ix0 + 1, iy1 = iy0 + 1;
    const float wx1 = xs - x0f, wx0 = 1.0f - wx1;
    const float wy1 = ys - y0f, wy0 = 1.0f - wy1;

    const float mx0 = (ix0 >= 0 && ix0 < 128) ? 1.0f : 0.0f;
    const float mx1 = (ix1 >= 0 && ix1 < 128) ? 1.0f : 0.0f;
    const float my0 = (iy0 >= 0 && iy0 < 256) ? 1.0f : 0.0f;
    const float my1 = (iy1 >= 0 && iy1 < 256) ? 1.0f : 0.0f;
    const int cx0 = min(max(ix0, 0), 127), cx1 = min(max(ix1, 0), 127);
    const int cy0 = min(max(iy0, 0), 255), cy1 = min(max(iy1, 0), 255);

    const float w00 = mx0 * my0 * wx0 * wy0, w10 = mx1 * my0 * wx1 * wy0;
    const float w01 = mx0 * my1 * wx0 * wy1, w11 = mx1 * my1 * wx1 * wy1;
    const int o00 = cy0 * 128 + cx0, o10 = cy0 * 128 + cx1;
    const int o01 = cy1 * 128 + cx0, o11 = cy1 * 128 + cx1;

    if (*flag) {
        const float* img = ((const float*)xv) + (size_t)n * 64 * 32768;
        for (int c = 0; c < 64; ++c) {
            const float* ic = img + c * 32768;
            const float r = ic[o00] * w00 + ic[o10] * w10 + ic[o01] * w01 + ic[o11] * w11;
            s_t[w * 66 + c] = f2bf(r);
        }
    } else {
        const unsigned short* img = ((const unsigned short*)xv) + (size_t)n * 64 * 32768;
        for (int c = 0; c < 64; ++c) {
            const unsigned short* ic = img + c * 32768;
            const float r = bf2f(ic[o00]) * w00 + bf2f(ic[o10]) * w10 +
                            bf2f(ic[o01]) * w01 + bf2f(ic[o11]) * w11;
            s_t[w * 66 + c] = f2bf(r);
        }
    }
    __syncthreads();
    // cooperative coalesced store: 128 px * 64 c = 4096 u32
    unsigned int* gout = (unsigned int*)(neighCL + ((size_t)n * 32768 + (size_t)h * 128) * 64);
    for (int e = w; e < 4096; e += 128) {
        const int px = e >> 5, part = e & 31;
        gout[px * 32 + part] = s_t32[px * 33 + part];
    }
}

// ============================================================
// MFMA conv kernels. LDS A-tile: 18 rows x (34 cols x 32ic + 8 pad) u16
// k' = kx*32 + icl contiguous; row stride 1096 u16 (2192 B -> 4-bank skew)
// ============================================================
#define ROWSTR 1096

// conv1: in neighCL [n][256][128][64] -> out c1CL [n][128][64][32], ReLU
__global__ __launch_bounds__(128) void k_conv1m(
    const unsigned short* __restrict__ in, const short* __restrict__ blob1,
    const float* __restrict__ P, unsigned short* __restrict__ out)
{
    __shared__ unsigned short s_a[18 * ROWSTR];
    __shared__ float sb[32];
    const int n = blockIdx.x;
    const int oy0 = blockIdx.y * 8;
    const int ox0 = blockIdx.z * 16;
    const int tid = threadIdx.x;
    const int wv = tid >> 6, lane = tid & 63;
    const int ln = lane & 15, q = lane >> 4;
    const int mrow = ln >> 2, mcol = ln & 3;
    const int iny0 = 2 * oy0 - 1, inx0 = 2 * ox0 - 1;
    if (tid < 32) sb[tid] = P[P_B1 + tid];

    floatx4 acc[4][2];
#pragma unroll
    for (int f = 0; f < 4; ++f)
#pragma unroll
        for (int t = 0; t < 2; ++t) acc[f][t] = (floatx4)0.0f;

    const ushort8 z8 = (ushort8)0;
    for (int c = 0; c < 2; ++c) {
        __syncthreads();
        for (int e = tid; e < 2448; e += 128) {
            const int row = e / 136, rem = e - row * 136;
            const int col = rem >> 2, part = rem & 3;
            const int gy = iny0 + row, gxp = inx0 + col;
            ushort8 v = z8;
            if (gy >= 0 && gy < 256 && gxp >= 0 && gxp < 128)
                v = *(const ushort8*)(in + (((size_t)n * 32768 + gy * 128 + gxp) * 64 + c * 32 + part * 8));
            *(ushort8*)(s_a + row * ROWSTR + col * 32 + part * 8) = v;
        }
        __syncthreads();
#pragma unroll
        for (int ky = 0; ky < 4; ++ky) {
            short8 bfr[4][2];
            const short* bb = blob1 + ((ky * 2 + c) * 8) * 512 + lane * 8;
#pragma unroll
            for (int s = 0; s < 4; ++s)
#pragma unroll
                for (int t = 0; t < 2; ++t)
                    bfr[s][t] = *(const short8*)(bb + (s * 2 + t) * 512);
#pragma unroll
            for (int f = 0; f < 4; ++f) {
                const int base = (2 * ((f >> 1) * 4 + mrow) + ky) * ROWSTR +
                                 (wv * 8 + (f & 1) * 4 + mcol) * 64 + q * 8;
#pragma unroll
                for (int s = 0; s < 4; ++s) {
                    const short8 a = *(const short8*)(s_a + base + s * 32);
#pragma unroll
                    for (int t = 0; t < 2; ++t)
                        acc[f][t] = __builtin_amdgcn_mfma_f32_16x16x32_bf16(a, bfr[s][t], acc[f][t], 0, 0, 0);
                }
            }
        }
    }
#pragma unroll
    for (int f = 0; f < 4; ++f)
#pragma unroll
        for (int t = 0; t < 2; ++t)
#pragma unroll
            for (int r = 0; r < 4; ++r) {
                const int oc = t * 16 + ln;
                const int oy = oy0 + (f >> 1) * 4 + q;
                const int ox = ox0 + wv * 8 + (f & 1) * 4 + r;
                float v = acc[f][t][r] + sb[oc];
                v = v > 0.0f ? v : 0.0f;
                out[(((size_t)n * 128 + oy) * 64 + ox) * 32 + oc] = f2bf(v);
            }
}

// conv2: in c1CL [n][128][64][32] -> out c2CL [n][64][32][64], ReLU
__global__ __launch_bounds__(256) void k_conv2m(
    const unsigned short* __restrict__ in, const short* __restrict__ blob2,
    const float* __restrict__ P, unsigned short* __restrict__ out)
{
    __shared__ unsigned short s_a[18 * ROWSTR];
    __shared__ float sb[64];
    const int n = blockIdx.x;
    const int oy0 = blockIdx.y * 8;
    const int ox0 = blockIdx.z * 16;
    const int tid = threadIdx.x;
    const int wave = tid >> 6, lane = tid & 63;
    const int wcol = wave & 1, wt = wave >> 1;
    const int ln = lane & 15, q = lane >> 4;
    const int mrow = ln >> 2, mcol = ln & 3;
    const int iny0 = 2 * oy0 - 1, inx0 = 2 * ox0 - 1;
    if (tid < 64) sb[tid] = P[P_B2 + tid];

    floatx4 acc[4][2];
#pragma unroll
    for (int f = 0; f < 4; ++f)
#pragma unroll
        for (int t = 0; t < 2; ++t) acc[f][t] = (floatx4)0.0f;

    const ushort8 z8 = (ushort8)0;
    for (int e = tid; e < 2448; e += 256) {
        const int row = e / 136, rem = e - row * 136;
        const int col = rem >> 2, part = rem & 3;
        const int gy = iny0 + row, gxp = inx0 + col;
        ushort8 v = z8;
        if (gy >= 0 && gy < 128 && gxp >= 0 && gxp < 64)
            v = *(const ushort8*)(in + (((size_t)n * 8192 + gy * 64 + gxp) * 32 + part * 8));
        *(ushort8*)(s_a + row * ROWSTR + col * 32 + part * 8) = v;
    }
    __syncthreads();
#pragma unroll
    for (int ky = 0; ky < 4; ++ky) {
        short8 bfr[4][2];
#pragma unroll
        for (int s = 0; s < 4; ++s)
#pragma unroll
            for (int tt = 0; tt < 2; ++tt)
                bfr[s][tt] = *(const short8*)(blob2 + ((ky * 4 + s) * 4 + wt * 2 + tt) * 512 + lane * 8);
#pragma unroll
        for (int f = 0; f < 4; ++f) {
            const int base = (2 * ((f >> 1) * 4 + mrow) + ky) * ROWSTR +
                             (wcol * 8 + (f & 1) * 4 + mcol) * 64 + q * 8;
#pragma unroll
            for (int s = 0; s < 4; ++s) {
                const short8 a = *(const short8*)(s_a + base + s * 32);
#pragma unroll
                for (int tt = 0; tt < 2; ++tt)
                    acc[f][tt] = __builtin_amdgcn_mfma_f32_16x16x32_bf16(a, bfr[s][tt], acc[f][tt], 0, 0, 0);
            }
        }
    }
#pragma unroll
    for (int f = 0; f < 4; ++f)
#pragma unroll
        for (int tt = 0; tt < 2; ++tt)
#pragma unroll
            for (int r = 0; r < 4; ++r) {
                const int oc = (wt * 2 + tt) * 16 + ln;
                const int oy = oy0 + (f >> 1) * 4 + q;
                const int ox = ox0 + wcol * 8 + (f & 1) * 4 + r;
                float v = acc[f][tt][r] + sb[oc];
                v = v > 0.0f ? v : 0.0f;
                out[(((size_t)n * 64 + oy) * 32 + ox) * 64 + oc] = f2bf(v);
            }
}

// conv3: in c2CL [n][64][32][64] -> ReLU -> pooled sums (20,64)
__global__ __launch_bounds__(256) void k_conv3m(
    const unsigned short* __restrict__ in, const short* __restrict__ blob3,
    const float* __restrict__ P, float* __restrict__ pooled)
{
    __shared__ unsigned short s_a[18 * ROWSTR];
    __shared__ float sb[64];
    const int n = blockIdx.x;
    const int oy0 = blockIdx.y * 8;
    const int tid = threadIdx.x;
    const int wave = tid >> 6, lane = tid & 63;
    const int wcol = wave & 1, wt = wave >> 1;
    const int ln = lane & 15, q = lane >> 4;
    const int mrow = ln >> 2, mcol = ln & 3;
    const int iny0 = 2 * oy0 - 1, inx0 = -1;
    if (tid < 64) sb[tid] = P[P_B3 + tid];

    floatx4 acc[4][2];
#pragma unroll
    for (int f = 0; f < 4; ++f)
#pragma unroll
        for (int t = 0; t < 2; ++t) acc[f][t] = (floatx4)0.0f;

    const ushort8 z8 = (ushort8)0;
    for (int c = 0; c < 2; ++c) {
        __syncthreads();
        for (int e = tid; e < 2448; e += 256) {
            const int row = e / 136, rem = e - row * 136;
            const int col = rem >> 2, part = rem & 3;
            const int gy = iny0 + row, gxp = inx0 + col;
            ushort8 v = z8;
            if (gy >= 0 && gy < 64 && gxp >= 0 && gxp < 32)
                v = *(const ushort8*)(in + (((size_t)n * 2048 + gy * 32 + gxp) * 64 + c * 32 + part * 8));
            *(ushort8*)(s_a + row * ROWSTR + col * 32 + part * 8) = v;
        }
        __syncthreads();
#pragma unroll
        for (int ky = 0; ky < 4; ++ky) {
            short8 bfr[4][2];
#pragma unroll
            for (int s = 0; s < 4; ++s)
#pragma unroll
                for (int tt = 0; tt < 2; ++tt)
                    bfr[s][tt] = *(const short8*)(blob3 + (((ky * 2 + c) * 4 + s) * 4 + wt * 2 + tt) * 512 + lane * 8);
#pragma unroll
            for (int f = 0; f < 4; ++f) {
                const int base = (2 * ((f >> 1) * 4 + mrow) + ky) * ROWSTR +
                                 (wcol * 8 + (f & 1) * 4 + mcol) * 64 + q * 8;
#pragma unroll
                for (int s = 0; s < 4; ++s) {
                    const short8 a = *(const short8*)(s_a + base + s * 32);
#pragma unroll
                    for (int tt = 0; tt < 2; ++tt)
                        acc[f][tt] = __builtin_amdgcn_mfma_f32_16x16x32_bf16(a, bfr[s][tt], acc[f][tt], 0, 0, 0);
                }
            }
        }
    }
    // ReLU(x+b), sum over this wave's 64 pixels, atomic into pooled
#pragma unroll
    for (int tt = 0; tt < 2; ++tt) {
        const int oc = (wt * 2 + tt) * 16 + ln;
        float ps = 0.0f;
#pragma unroll
        for (int f = 0; f < 4; ++f)
#pragma unroll
            for (int r = 0; r < 4; ++r) {
                float v = acc[f][tt][r] + sb[oc];
                ps += (v > 0.0f ? v : 0.0f);
            }
        ps += __shfl_xor(ps, 16, 64);
        ps += __shfl_xor(ps, 32, 64);
        if (lane < 16) atomicAdd(&pooled[n * 64 + oc], ps);
    }
}

// ============================================================
// K5: attention — MLPs + softmax. 4 blocks (per batch), 256 thr
// ============================================================
__global__ __launch_bounds__(256) void k_attn(
    const float* __restrict__ P,
    const float* __restrict__ pooled,       // (20,64) sums
    float* __restrict__ attn)               // (4,5)
{
    __shared__ float sfeat[320], sh1[1280], sh2[640], skeys[1280];
    __shared__ float sq1[256], sq2[128], sq3[32], sqv[256], sred[4], slog[5];
    const int b = blockIdx.x, t = threadIdx.x;

    for (int i = t; i < 320; i += 256) sfeat[i] = pooled[b * 320 + i] * (1.0f / 512.0f);
    __syncthreads();

    {
        const float* w = P + P_K1W; const float* bb = P + P_K1B;
        for (int l = 0; l < 5; ++l) {
            float s = bb[t];
            for (int c = 0; c < 64; ++c) s += w[t * 64 + c] * sfeat[l * 64 + c];
            sh1[l * 256 + t] = fmaxf(s, 0.0f);
        }
        const float* wq = P + P_Q1W; const float* bq = P + P_Q1B;
        float s = bq[t];
        for (int c = 0; c < 64; ++c) s += wq[t * 64 + c] * sfeat[c];
        sq1[t] = fmaxf(s, 0.0f);
    }
    __syncthreads();
    if (t < 128) {
        const float* w = P + P_K2W; const float* bb = P + P_K2B;
        for (int l = 0; l < 5; ++l) {
            float s = bb[t];
            for (int k = 0; k < 256; ++k) s += w[t * 256 + k] * sh1[l * 256 + k];
            sh2[l * 128 + t] = fmaxf(s, 0.0f);
        }
        const float* wq = P + P_Q2W; const float* bq = P + P_Q2B;
        float s = bq[t];
        for (int k = 0; k < 256; ++k) s += wq[t * 256 + k] * sq1[k];
        sq2[t] = fmaxf(s, 0.0f);
    }
    __syncthreads();
    {
        const float* w = P + P_K3W; const float* bb = P + P_K3B;
        for (int l = 0; l < 5; ++l) {
            float s = bb[t];
            for (int k = 0; k < 128; ++k) s += w[t * 128 + k] * sh2[l * 128 + k];
            skeys[l * 256 + t] = s;   // no relu on layer 3
        }
    }
    if (t < 32) {
        const float* wq = P + P_Q3W; const float* bq = P + P_Q3B;
        float s = bq[t];
        for (int k = 0; k < 128; ++k) s += wq[t * 128 + k] * sq2[k];
        sq3[t] = s;
    }
    __syncthreads();
    {
        const float* w = P + P_AW; const float* bb = P + P_AB;
        float s = bb[t];
        for (int k = 0; k < 32; ++k) s += w[t * 32 + k] * sq3[k];
        sqv[t] = s;
    }
    __syncthreads();
    for (int l = 0; l < 5; ++l) {
        float v = skeys[l * 256 + t] * sqv[t];
        for (int off = 32; off > 0; off >>= 1) v += __shfl_down(v, off, 64);
        if ((t & 63) == 0) sred[t >> 6] = v;
        __syncthreads();
        if (t == 0) slog[l] = sred[0] + sred[1] + sred[2] + sred[3];
        __syncthreads();
    }
    if (t == 0) {
        float m = slog[0];
        for (int l = 1; l < 5; ++l) m = fmaxf(m, slog[l]);
        float e[5], s = 0.0f;
        for (int l = 0; l < 5; ++l) { e[l] = expf(slog[l] - m); s += e[l]; }
        const float inv = 1.0f / s;
        for (int l = 0; l < 5; ++l) attn[b * 5 + l] = e[l] * inv;
    }
}

// ============================================================
// K6: out[b,c,h,w] = sum_l attn[b,l]*neighCL[b,l,h,w,c]  (fp32 out, ch-first)
// block: 64 px x 64 c; 256 thr (4 thr/px)
// ============================================================
__global__ __launch_bounds__(256) void k_final(
    const unsigned short* __restrict__ neighCL,
    const float* __restrict__ attn,
    float* __restrict__ out)
{
    const int blk = blockIdx.x;
    const int b = blk >> 9;
    const int px0 = (blk & 511) << 6;
    const int t = threadIdx.x;
    const int p = t >> 2, part = t & 3;
    const float* a = attn + b * 5;
    float acc[16];
#pragma unroll
    for (int i = 0; i < 16; ++i) acc[i] = 0.0f;
#pragma unroll
    for (int l = 0; l < 5; ++l) {
        const ushort8* src = (const ushort8*)(neighCL +
            (((size_t)(b * 5 + l) * 32768 + px0 + p) * 64 + part * 16));
        const ushort8 v0 = src[0], v1 = src[1];
        const float wl = a[l];
#pragma unroll
        for (int j = 0; j < 8; ++j) {
            acc[j]     += wl * bf2f(v0[j]);
            acc[8 + j] += wl * bf2f(v1[j]);
        }
    }
#pragma unroll
    for (int ch = 0; ch < 2; ++ch)
#pragma unroll
        for (int j = 0; j < 8; ++j) {
            const int c = part * 16 + ch * 8 + j;
            out[((size_t)b * 64 + c) * 32768 + px0 + p] = acc[ch * 8 + j];
        }
}

// ============================================================
extern "C" void kernel_launch(void* const* d_in, const int* in_sizes, int n_in,
                              void* d_out, int out_size, void* d_ws, size_t ws_size,
                              hipStream_t stream) {
    // workspace layout (bytes)
    const size_t OFF_FLAG  = 0;
    const size_t OFF_PARAM = 256;                       // 145432*4 = 581,728
    const size_t OFF_BLOB  = 582016;                    // 131072 bf16 = 262,144
    const size_t OFF_NEIGH = 844160;                    // 20*256*128*64 bf16 = 83,886,080
    const size_t OFF_C1    = OFF_NEIGH + 83886080;      // 20*128*64*32 bf16 = 10,485,760
    const size_t OFF_C2    = OFF_C1 + 10485760;         // 20*64*32*64 bf16 = 5,242,880
    const size_t OFF_POOL  = OFF_C2 + 5242880;          // 20*64 f32
    const size_t OFF_ATTN  = OFF_POOL + 5120;
    const size_t NEED      = OFF_ATTN + 80;
    if (ws_size < NEED) return;

    char* ws = (char*)d_ws;
    int*   flag   = (int*)(ws + OFF_FLAG);
    float* params = (float*)(ws + OFF_PARAM);
    short* blobs  = (short*)(ws + OFF_BLOB);
    unsigned short* neighCL = (unsigned short*)(ws + OFF_NEIGH);
    unsigned short* c1      = (unsigned short*)(ws + OFF_C1);
    unsigned short* c2      = (unsigned short*)(ws + OFF_C2);
    float* pooled           = (float*)(ws + OFF_POOL);
    float* attn             = (float*)(ws + OFF_ATTN);

    ParamDesc pd;
    const int srcIdx[18] = {2,4,6,8,9,10,11,12,13,14,15,16,17,18,19,20,21,22};
    const int lens[18]   = {600,32,64,64,16384,256,32768,128,32768,256,
                            16384,256,32768,128,4096,32,8192,256};
    const int dsts[18]   = {P_NAM,P_B1,P_B2,P_B3,P_K1W,P_K1B,P_K2W,P_K2B,P_K3W,P_K3B,
                            P_Q1W,P_Q1B,P_Q2W,P_Q2B,P_Q3W,P_Q3B,P_AW,P_AB};
    for (int t = 0; t < 18; ++t) {
        pd.src[t] = d_in[srcIdx[t]];
        pd.len[t] = lens[t];
        pd.dst[t] = dsts[t];
    }

    hipMemsetAsync(pooled, 0, 5120, stream);

    k_detect<<<1, 64, 0, stream>>>((const unsigned short*)d_in[0], flag);
    k_convert<<<569, 256, 0, stream>>>(pd, flag, params);
    k_pack<<<512, 256, 0, stream>>>(d_in[3], d_in[5], d_in[7], flag, blobs);
    k_gridsample<<<dim3(20, 256), 128, 0, stream>>>(d_in[0], params, flag, neighCL);
    k_conv1m<<<dim3(20, 16, 4), 128, 0, stream>>>(neighCL, blobs, params, c1);
    k_conv2m<<<dim3(20, 8, 2), 256, 0, stream>>>(c1, blobs + 32768, params, c2);
    k_conv3m<<<dim3(20, 4, 1), 256, 0, stream>>>(c2, blobs + 65536, params, pooled);
    k_attn<<<4, 256, 0, stream>>>(params, pooled, attn);
    k_final<<<2048, 256, 0, stream>>>(neighCL, attn, (float*)d_out);
}